// Round 1
// baseline (850.953 us; speedup 1.0000x reference)
//
#include <hip/hip_runtime.h>

// Problem constants
#define NR 8192     // B*L rows
#define DM 512      // model dim (= H*DK = H*DV = DOUT = DMQ = DMV)
#define NH 8
#define HD 64       // head dim

// ---------------------------------------------------------------------------
// GEMM: C[M=8192, N=512] = A[8192,512] * W[512,512] (+bias) (+relu)
// 64x64 tile per block, 256 threads, 4x4 register blocking.
// ---------------------------------------------------------------------------
template<bool RELU, bool BIAS>
__global__ __launch_bounds__(256)
void gemm_kernel(const float* __restrict__ A, const float* __restrict__ W,
                 const float* __restrict__ bias, float* __restrict__ C)
{
    __shared__ float As[16][68];  // [k][m], +4 pad -> odd 16B-unit stride
    __shared__ float Bs[16][68];  // [k][n]
    const int t  = threadIdx.x;
    const int tx = t & 15, ty = t >> 4;
    const int m0 = blockIdx.x * 64, n0 = blockIdx.y * 64;

    float acc[4][4] = {};

    for (int kb = 0; kb < DM; kb += 16) {
        // A tile: 64 rows x 16 k  -> As[k][m]
        #pragma unroll
        for (int i = t; i < 64 * 16; i += 256) {
            int m = i >> 4, k = i & 15;
            As[k][m] = A[(size_t)(m0 + m) * DM + kb + k];
        }
        // W tile: 16 k x 64 n -> Bs[k][n]
        #pragma unroll
        for (int i = t; i < 16 * 64; i += 256) {
            int k = i >> 6, n = i & 63;
            Bs[k][n] = W[(size_t)(kb + k) * DM + n0 + n];
        }
        __syncthreads();
        #pragma unroll
        for (int k = 0; k < 16; ++k) {
            float4 a4 = *(const float4*)&As[k][ty * 4];
            float4 b4 = *(const float4*)&Bs[k][tx * 4];
            const float a[4] = {a4.x, a4.y, a4.z, a4.w};
            const float b[4] = {b4.x, b4.y, b4.z, b4.w};
            #pragma unroll
            for (int i = 0; i < 4; ++i)
                #pragma unroll
                for (int j = 0; j < 4; ++j)
                    acc[i][j] += a[i] * b[j];
        }
        __syncthreads();
    }

    #pragma unroll
    for (int i = 0; i < 4; ++i) {
        int m = m0 + ty * 4 + i;
        int n = n0 + tx * 4;
        float4 v = {acc[i][0], acc[i][1], acc[i][2], acc[i][3]};
        if (BIAS) {
            v.x += bias[n + 0]; v.y += bias[n + 1];
            v.z += bias[n + 2]; v.w += bias[n + 3];
        }
        if (RELU) {
            v.x = fmaxf(v.x, 0.f); v.y = fmaxf(v.y, 0.f);
            v.z = fmaxf(v.z, 0.f); v.w = fmaxf(v.w, 0.f);
        }
        *(float4*)&C[(size_t)m * DM + n] = v;
    }
}

// ---------------------------------------------------------------------------
// LayerNorm over rows of 512 (in-place capable). Optionally writes raw input
// (pre-LN) to `res` (the residual output).
// ---------------------------------------------------------------------------
__global__ __launch_bounds__(256)
void ln_kernel(const float* __restrict__ P, const float* __restrict__ gm,
               const float* __restrict__ be, float* __restrict__ out,
               float* __restrict__ res)
{
    const int row = blockIdx.x;
    const int t = threadIdx.x;
    const size_t off = (size_t)row * DM + t * 2;
    float2 v = *(const float2*)(P + off);
    if (res) *(float2*)(res + off) = v;

    float s  = v.x + v.y;
    float s2 = v.x * v.x + v.y * v.y;
    #pragma unroll
    for (int o = 32; o; o >>= 1) {
        s  += __shfl_down(s,  o);
        s2 += __shfl_down(s2, o);
    }
    __shared__ float ss[4], ss2[4];
    const int lane = t & 63, w = t >> 6;
    if (lane == 0) { ss[w] = s; ss2[w] = s2; }
    __syncthreads();
    float S  = ss[0] + ss[1] + ss[2] + ss[3];
    float S2 = ss2[0] + ss2[1] + ss2[2] + ss2[3];
    float mu  = S * (1.f / DM);
    float var = S2 * (1.f / DM) - mu * mu;
    float rs  = rsqrtf(var + 1e-6f);
    float2 o;
    o.x = (v.x - mu) * rs * gm[t * 2 + 0] + be[t * 2 + 0];
    o.y = (v.y - mu) * rs * gm[t * 2 + 1] + be[t * 2 + 1];
    *(float2*)(out + off) = o;
}

// ---------------------------------------------------------------------------
// Flash attention, f32. Block = (qtile=64 rows) x (b,h). 256 threads.
// Thread t: row r = t&63 of the q-tile, group g = t>>6 owns 16 k-cols of S/P
// and 16 d-cols of O.
// ---------------------------------------------------------------------------
__global__ __launch_bounds__(256)
void attn_kernel(const float* __restrict__ qn, const float* __restrict__ kn,
                 const float* __restrict__ vn, float* __restrict__ outp)
{
    __shared__ float Qs[64][68];
    __shared__ float Ks[64][68];
    __shared__ float Vs[64][68];
    __shared__ float Ps[64][68];
    __shared__ float redA[4][64];
    __shared__ float redB[4][64];

    const int qt = blockIdx.x, h = blockIdx.y, b = blockIdx.z;
    const int t = threadIdx.x;
    const int r = t & 63, g = t >> 6;

    const size_t base = (size_t)b * 1024 * DM + h * HD;
    const float* Q = qn + base + (size_t)qt * 64 * DM;
    const float* K = kn + base;
    const float* V = vn + base;

    for (int i = t; i < 64 * 64; i += 256) {
        int rr = i >> 6, d = i & 63;
        Qs[rr][d] = Q[(size_t)rr * DM + d];
    }
    float o[16];
    #pragma unroll
    for (int i = 0; i < 16; ++i) o[i] = 0.f;
    float m_r = -1e30f, l_r = 0.f;
    __syncthreads();

    for (int kt = 0; kt < 16; ++kt) {
        for (int i = t; i < 64 * 64; i += 256) {
            int rr = i >> 6, d = i & 63;
            Ks[rr][d] = K[(size_t)(kt * 64 + rr) * DM + d];
            Vs[rr][d] = V[(size_t)(kt * 64 + rr) * DM + d];
        }
        __syncthreads();

        // S[r][g*16+c] = Q[r]·K[c] * 0.125
        float s[16];
        #pragma unroll
        for (int i = 0; i < 16; ++i) s[i] = 0.f;
        #pragma unroll 4
        for (int d4 = 0; d4 < 16; ++d4) {
            float4 q4 = *(const float4*)&Qs[r][d4 * 4];
            #pragma unroll
            for (int c = 0; c < 16; ++c) {
                float4 k4 = *(const float4*)&Ks[g * 16 + c][d4 * 4];
                s[c] += q4.x * k4.x + q4.y * k4.y + q4.z * k4.z + q4.w * k4.w;
            }
        }
        float lmax = -1e30f;
        #pragma unroll
        for (int i = 0; i < 16; ++i) { s[i] *= 0.125f; lmax = fmaxf(lmax, s[i]); }
        redA[g][r] = lmax;
        __syncthreads();

        float m_tile = fmaxf(fmaxf(redA[0][r], redA[1][r]),
                             fmaxf(redA[2][r], redA[3][r]));
        float m_new = fmaxf(m_r, m_tile);
        float alpha = __expf(m_r - m_new);
        float p[16];
        float lsum = 0.f;
        #pragma unroll
        for (int i = 0; i < 16; ++i) { p[i] = __expf(s[i] - m_new); lsum += p[i]; }
        redB[g][r] = lsum;
        #pragma unroll
        for (int i4 = 0; i4 < 4; ++i4) {
            float4 pv = {p[i4*4], p[i4*4+1], p[i4*4+2], p[i4*4+3]};
            *(float4*)&Ps[r][g * 16 + i4 * 4] = pv;
        }
        __syncthreads();

        float tsum = redB[0][r] + redB[1][r] + redB[2][r] + redB[3][r];
        l_r = l_r * alpha + tsum;
        m_r = m_new;
        #pragma unroll
        for (int i = 0; i < 16; ++i) o[i] *= alpha;

        #pragma unroll 4
        for (int k4 = 0; k4 < 16; ++k4) {
            float4 p4 = *(const float4*)&Ps[r][k4 * 4];
            const float pk4[4] = {p4.x, p4.y, p4.z, p4.w};
            #pragma unroll
            for (int kk = 0; kk < 4; ++kk) {
                float pk = pk4[kk];
                const float* vrow = &Vs[k4 * 4 + kk][g * 16];
                float4 v0 = *(const float4*)(vrow + 0);
                float4 v1 = *(const float4*)(vrow + 4);
                float4 v2 = *(const float4*)(vrow + 8);
                float4 v3 = *(const float4*)(vrow + 12);
                o[0]  += pk * v0.x; o[1]  += pk * v0.y; o[2]  += pk * v0.z; o[3]  += pk * v0.w;
                o[4]  += pk * v1.x; o[5]  += pk * v1.y; o[6]  += pk * v1.z; o[7]  += pk * v1.w;
                o[8]  += pk * v2.x; o[9]  += pk * v2.y; o[10] += pk * v2.z; o[11] += pk * v2.w;
                o[12] += pk * v3.x; o[13] += pk * v3.y; o[14] += pk * v3.z; o[15] += pk * v3.w;
            }
        }
        __syncthreads();
    }

    float inv = 1.f / l_r;
    size_t ob = ((size_t)b * 1024 + qt * 64 + r) * DM + h * HD + g * 16;
    #pragma unroll
    for (int i4 = 0; i4 < 4; ++i4) {
        float4 ov = {o[i4*4] * inv, o[i4*4+1] * inv, o[i4*4+2] * inv, o[i4*4+3] * inv};
        *(float4*)&outp[ob + i4 * 4] = ov;
    }
}

// ---------------------------------------------------------------------------
extern "C" void kernel_launch(void* const* d_in, const int* in_sizes, int n_in,
                              void* d_out, int out_size, void* d_ws, size_t ws_size,
                              hipStream_t stream)
{
    const float* q    = (const float*)d_in[0];
    const float* k    = (const float*)d_in[1];
    const float* v    = (const float*)d_in[2];
    const float* Wq   = (const float*)d_in[3];
    const float* bq   = (const float*)d_in[4];
    const float* Wk   = (const float*)d_in[5];
    const float* bk   = (const float*)d_in[6];
    const float* Wv   = (const float*)d_in[7];
    const float* bv   = (const float*)d_in[8];
    const float* g_q  = (const float*)d_in[9];
    const float* be_q = (const float*)d_in[10];
    const float* g_k  = (const float*)d_in[11];
    const float* be_k = (const float*)d_in[12];
    const float* g_v  = (const float*)d_in[13];
    const float* be_v = (const float*)d_in[14];
    const float* W1   = (const float*)d_in[15];
    const float* b1   = (const float*)d_in[16];
    const float* W2   = (const float*)d_in[17];
    const float* b2   = (const float*)d_in[18];

    float* out = (float*)d_out;                 // [8192, 512] final FFN output
    float* res = out + (size_t)NR * DM;         // [8192, 512] residual (raw qp)

    float* qb = (float*)d_ws;                   // qp -> qn (in-place LN)
    float* kb = qb + (size_t)NR * DM;
    float* vb = kb + (size_t)NR * DM;
    float* ab = vb + (size_t)NR * DM;           // attention output
    float* hb = qb;                             // FFN hidden reuses q buffer

    dim3 gg(NR / 64, DM / 64), gb(256);

    gemm_kernel<false, true><<<gg, gb, 0, stream>>>(q, Wq, bq, qb);
    gemm_kernel<false, true><<<gg, gb, 0, stream>>>(k, Wk, bk, kb);
    gemm_kernel<false, true><<<gg, gb, 0, stream>>>(v, Wv, bv, vb);

    ln_kernel<<<NR, 256, 0, stream>>>(qb, g_q, be_q, qb, res);
    ln_kernel<<<NR, 256, 0, stream>>>(kb, g_k, be_k, kb, nullptr);
    ln_kernel<<<NR, 256, 0, stream>>>(vb, g_v, be_v, vb, nullptr);

    attn_kernel<<<dim3(16, NH, 8), 256, 0, stream>>>(qb, kb, vb, ab);

    gemm_kernel<true,  true><<<gg, gb, 0, stream>>>(ab, W1, b1, hb);
    gemm_kernel<false, true><<<gg, gb, 0, stream>>>(hb, W2, b2, out);
}

// Round 2
// 192.450 us; speedup vs baseline: 4.4217x; 4.4217x over previous
//
#include <hip/hip_runtime.h>
#include <stdint.h>

typedef unsigned short u16;
typedef __attribute__((ext_vector_type(8))) short bf16x8;
typedef __attribute__((ext_vector_type(4))) float f32x4;

#define NR 8192     // B*L rows
#define DM 512      // model dim
#define NH 8
#define HD 64
#define LQ 1024

__device__ __forceinline__ u16 f2b(float f) {
    union { float f; uint32_t u; } v; v.f = f;
    uint32_t r = v.u + 0x7fffu + ((v.u >> 16) & 1u);   // RNE
    return (u16)(r >> 16);
}

// ---------------------------------------------------------------------------
// f32 -> bf16 bulk convert (8 elems/thread, exact-size grid)
// ---------------------------------------------------------------------------
__global__ __launch_bounds__(256)
void conv_bf16_kernel(const float* __restrict__ in, u16* __restrict__ out)
{
    const int i = blockIdx.x * 256 + threadIdx.x;
    const float4* p = (const float4*)in + (size_t)i * 2;
    float4 a = p[0], b = p[1];
    uint4 o;
    o.x = (uint32_t)f2b(a.x) | ((uint32_t)f2b(a.y) << 16);
    o.y = (uint32_t)f2b(a.z) | ((uint32_t)f2b(a.w) << 16);
    o.z = (uint32_t)f2b(b.x) | ((uint32_t)f2b(b.y) << 16);
    o.w = (uint32_t)f2b(b.z) | ((uint32_t)f2b(b.w) << 16);
    ((uint4*)out)[i] = o;
}

// ---------------------------------------------------------------------------
// W [K=512][N=512] f32  ->  Wt [N][K] bf16  (64x64 LDS tile transpose)
// ---------------------------------------------------------------------------
__global__ __launch_bounds__(256)
void wt_kernel(const float* __restrict__ W, u16* __restrict__ Wt)
{
    __shared__ float S[64][65];
    const int k0 = blockIdx.x * 64, n0 = blockIdx.y * 64;
    #pragma unroll
    for (int p = 0; p < 16; ++p) {
        int idx = threadIdx.x + p * 256;
        int r = idx >> 6, c = idx & 63;
        S[r][c] = W[(size_t)(k0 + r) * DM + n0 + c];
    }
    __syncthreads();
    #pragma unroll
    for (int p = 0; p < 16; ++p) {
        int idx = threadIdx.x + p * 256;
        int r = idx >> 6, c = idx & 63;
        Wt[(size_t)(n0 + r) * DM + k0 + c] = f2b(S[c][r]);
    }
}

// ---------------------------------------------------------------------------
// LayerNorm rows of 512, f32 in -> bf16 out, gamma/beta scaled by `scale`
// (scale=0.125 for q folds in the 1/sqrt(DK) attention scale)
// ---------------------------------------------------------------------------
__global__ __launch_bounds__(256)
void ln_bf16_kernel(const float* __restrict__ P, const float* __restrict__ gm,
                    const float* __restrict__ be, u16* __restrict__ out, float scale)
{
    const int row = blockIdx.x, t = threadIdx.x;
    const size_t off = (size_t)row * DM + t * 2;
    float2 v = *(const float2*)(P + off);
    float s = v.x + v.y, s2 = v.x * v.x + v.y * v.y;
    #pragma unroll
    for (int o = 32; o; o >>= 1) { s += __shfl_down(s, o); s2 += __shfl_down(s2, o); }
    __shared__ float ss[4], ss2[4];
    if ((t & 63) == 0) { ss[t >> 6] = s; ss2[t >> 6] = s2; }
    __syncthreads();
    float S = ss[0] + ss[1] + ss[2] + ss[3];
    float S2 = ss2[0] + ss2[1] + ss2[2] + ss2[3];
    float mu = S * (1.f / DM);
    float var = S2 * (1.f / DM) - mu * mu;
    float rs = rsqrtf(var + 1e-6f);
    float g0 = gm[t * 2] * scale, g1 = gm[t * 2 + 1] * scale;
    float b0 = be[t * 2] * scale, b1 = be[t * 2 + 1] * scale;
    float o0 = (v.x - mu) * rs * g0 + b0;
    float o1 = (v.y - mu) * rs * g1 + b1;
    uint32_t pk = (uint32_t)f2b(o0) | ((uint32_t)f2b(o1) << 16);
    *(uint32_t*)(out + off) = pk;
}

// ---------------------------------------------------------------------------
// bf16 MFMA GEMM: C[M,N=512] = A[M,K=512] * Bt[N,K]^T (+bias)(+relu)
// 128x128 tile, 512 threads = 8 waves (2m x 4n), each wave 64x32.
// LDS layout: 16B units [granule g=k/8 (4)][row (128)] -> conflict-free b128.
// Reg-staged with prefetch (issue-early / write-late).
// ---------------------------------------------------------------------------
template<bool RELU, bool OUT_BF16>
__global__ __launch_bounds__(512)
void mfma_gemm_kernel(const u16* __restrict__ A, const u16* __restrict__ Bt,
                      const float* __restrict__ bias, void* __restrict__ Cout)
{
    __shared__ u16 Al[4 * 128 * 8];
    __shared__ u16 Bl[4 * 128 * 8];
    const int t = threadIdx.x;
    const int w = t >> 6, l = t & 63;
    const int m0 = blockIdx.x * 128, n0 = blockIdx.y * 128;
    const int sg = w & 3, sr = (w >> 2) * 64;   // staging granule / row-base
    const int wm = w >> 2, wn = w & 3;          // wave tile coords

    const u16* Ap = A  + (size_t)(m0 + sr + l) * DM + sg * 8;
    const u16* Bp = Bt + (size_t)(n0 + sr + l) * DM + sg * 8;
    const int su = (sg * 128 + sr + l) * 8;

    uint4 ga = *(const uint4*)Ap;
    uint4 gb = *(const uint4*)Bp;

    f32x4 acc[4][2];
    #pragma unroll
    for (int mi = 0; mi < 4; ++mi)
        #pragma unroll
        for (int ni = 0; ni < 2; ++ni)
            acc[mi][ni] = {0.f, 0.f, 0.f, 0.f};

    for (int kb = 0; kb < DM / 32; ++kb) {
        __syncthreads();                 // prev-iter frag reads done
        *(uint4*)&Al[su] = ga;
        *(uint4*)&Bl[su] = gb;
        if (kb + 1 < DM / 32) {
            ga = *(const uint4*)(Ap + (kb + 1) * 32);
            gb = *(const uint4*)(Bp + (kb + 1) * 32);
        }
        __syncthreads();                 // tile staged
        bf16x8 af[4], bfr[2];
        #pragma unroll
        for (int mi = 0; mi < 4; ++mi)
            af[mi] = *(const bf16x8*)&Al[((l >> 4) * 128 + wm * 64 + mi * 16 + (l & 15)) * 8];
        #pragma unroll
        for (int ni = 0; ni < 2; ++ni)
            bfr[ni] = *(const bf16x8*)&Bl[((l >> 4) * 128 + wn * 32 + ni * 16 + (l & 15)) * 8];
        #pragma unroll
        for (int mi = 0; mi < 4; ++mi)
            #pragma unroll
            for (int ni = 0; ni < 2; ++ni)
                acc[mi][ni] = __builtin_amdgcn_mfma_f32_16x16x32_bf16(af[mi], bfr[ni], acc[mi][ni], 0, 0, 0);
    }

    const int cq = l >> 4, cr = l & 15;
    #pragma unroll
    for (int mi = 0; mi < 4; ++mi) {
        const int row = m0 + wm * 64 + mi * 16 + cq * 4;
        #pragma unroll
        for (int ni = 0; ni < 2; ++ni) {
            const int col = n0 + wn * 32 + ni * 16 + cr;
            const float bb = bias[col];
            #pragma unroll
            for (int j = 0; j < 4; ++j) {
                float vv = acc[mi][ni][j] + bb;
                if (RELU) vv = fmaxf(vv, 0.f);
                if (OUT_BF16) ((u16*)Cout)[(size_t)(row + j) * DM + col] = f2b(vv);
                else          ((float*)Cout)[(size_t)(row + j) * DM + col] = vv;
            }
        }
    }
}

// ---------------------------------------------------------------------------
// MFMA flash attention. Block = 64 q-rows x (b,h); 4 waves, 16 q-rows each.
// Q frags in registers; K in LDS units [gd(8)][kv(64)]; V transposed into
// LDS units [gkv(8)][d^gkv (64)] (XOR keeps staging writes conflict-free);
// per-wave P round-trip through LDS units [gkv(8)][row(16)].
// Online softmax in-register: row r owned by 16-lane group (C/D layout
// row=(l>>4)*4+j, col=l&15), reduced via shfl_xor 1/2/4/8.
// ---------------------------------------------------------------------------
__global__ __launch_bounds__(256)
void attn_mfma_kernel(const u16* __restrict__ qn, const u16* __restrict__ kn,
                      const u16* __restrict__ vn, u16* __restrict__ ab)
{
    __shared__ u16 Kl[8 * 64 * 8];
    __shared__ u16 Vt[8 * 64 * 8];
    __shared__ u16 Pl[4][8 * 16 * 8];

    const int t = threadIdx.x;
    const int w = t >> 6, l = t & 63;
    const int qt = blockIdx.x, h = blockIdx.y, b = blockIdx.z;
    const size_t bbase = (size_t)b * LQ * DM + h * HD;

    bf16x8 qf[2];
    {
        const u16* qrow = qn + bbase + (size_t)(qt * 64 + w * 16 + (l & 15)) * DM + (l >> 4) * 8;
        qf[0] = *(const bf16x8*)(qrow);
        qf[1] = *(const bf16x8*)(qrow + 32);
    }

    f32x4 of[4];
    #pragma unroll
    for (int ni = 0; ni < 4; ++ni) of[ni] = {0.f, 0.f, 0.f, 0.f};
    float mrun[4], lrun[4];
    #pragma unroll
    for (int j = 0; j < 4; ++j) { mrun[j] = -1e30f; lrun[j] = 0.f; }

    const int srow = t >> 2, schk = t & 3;      // staging: kv row, 16-elem d-chunk
    const int gkv = srow >> 3, ik = srow & 7;
    const u16* Kg = kn + bbase + (size_t)srow * DM + schk * 16;
    const u16* Vg = vn + bbase + (size_t)srow * DM + schk * 16;

    for (int kt = 0; kt < 16; ++kt) {
        const size_t roff = (size_t)kt * 64 * DM;
        uint4 ka  = *(const uint4*)(Kg + roff);
        uint4 kb2 = *(const uint4*)(Kg + roff + 8);
        uint4 va  = *(const uint4*)(Vg + roff);
        uint4 vb2 = *(const uint4*)(Vg + roff + 8);
        *(uint4*)&Kl[((schk * 2 + 0) * 64 + srow) * 8] = ka;
        *(uint4*)&Kl[((schk * 2 + 1) * 64 + srow) * 8] = kb2;
        u16 tv[16];
        *(uint4*)&tv[0] = va;
        *(uint4*)&tv[8] = vb2;
        #pragma unroll
        for (int e = 0; e < 16; ++e) {
            int d = schk * 16 + e;
            Vt[(gkv * 64 + (d ^ gkv)) * 8 + ik] = tv[e];
        }
        __syncthreads();

        // ---- S = Q K^T (scale pre-folded into LN-q gamma/beta)
        f32x4 s[4];
        #pragma unroll
        for (int ni = 0; ni < 4; ++ni) s[ni] = {0.f, 0.f, 0.f, 0.f};
        #pragma unroll
        for (int kk = 0; kk < 2; ++kk) {
            #pragma unroll
            for (int ni = 0; ni < 4; ++ni) {
                bf16x8 kf = *(const bf16x8*)&Kl[((kk * 4 + (l >> 4)) * 64 + ni * 16 + (l & 15)) * 8];
                s[ni] = __builtin_amdgcn_mfma_f32_16x16x32_bf16(qf[kk], kf, s[ni], 0, 0, 0);
            }
        }

        // ---- online softmax (rows owned within 16-lane groups)
        float tmax[4];
        #pragma unroll
        for (int j = 0; j < 4; ++j)
            tmax[j] = fmaxf(fmaxf(s[0][j], s[1][j]), fmaxf(s[2][j], s[3][j]));
        #pragma unroll
        for (int j = 0; j < 4; ++j) {
            tmax[j] = fmaxf(tmax[j], __shfl_xor(tmax[j], 1));
            tmax[j] = fmaxf(tmax[j], __shfl_xor(tmax[j], 2));
            tmax[j] = fmaxf(tmax[j], __shfl_xor(tmax[j], 4));
            tmax[j] = fmaxf(tmax[j], __shfl_xor(tmax[j], 8));
        }
        float alpha[4], psum[4];
        #pragma unroll
        for (int j = 0; j < 4; ++j) {
            float mn = fmaxf(mrun[j], tmax[j]);
            alpha[j] = __expf(mrun[j] - mn);
            mrun[j] = mn;
        }
        #pragma unroll
        for (int ni = 0; ni < 4; ++ni)
            #pragma unroll
            for (int j = 0; j < 4; ++j)
                s[ni][j] = __expf(s[ni][j] - mrun[j]);
        #pragma unroll
        for (int j = 0; j < 4; ++j) {
            psum[j] = s[0][j] + s[1][j] + s[2][j] + s[3][j];
            psum[j] += __shfl_xor(psum[j], 1);
            psum[j] += __shfl_xor(psum[j], 2);
            psum[j] += __shfl_xor(psum[j], 4);
            psum[j] += __shfl_xor(psum[j], 8);
            lrun[j] = lrun[j] * alpha[j] + psum[j];
        }
        #pragma unroll
        for (int ni = 0; ni < 4; ++ni)
            #pragma unroll
            for (int j = 0; j < 4; ++j)
                of[ni][j] *= alpha[j];

        // ---- P -> per-wave LDS (bf16, A-frag-ready units)
        #pragma unroll
        for (int ni = 0; ni < 4; ++ni) {
            const int gk = ((l & 15) >> 3) + 2 * ni;
            #pragma unroll
            for (int j = 0; j < 4; ++j) {
                const int row = (l >> 4) * 4 + j;
                Pl[w][(gk * 16 + row) * 8 + (l & 7)] = f2b(s[ni][j]);
            }
        }

        // ---- O += P V
        #pragma unroll
        for (int kkv = 0; kkv < 2; ++kkv) {
            const int gg = kkv * 4 + (l >> 4);
            bf16x8 pa = *(const bf16x8*)&Pl[w][(gg * 16 + (l & 15)) * 8];
            #pragma unroll
            for (int ni = 0; ni < 4; ++ni) {
                bf16x8 vf = *(const bf16x8*)&Vt[(gg * 64 + ((ni * 16 + (l & 15)) ^ gg)) * 8];
                of[ni] = __builtin_amdgcn_mfma_f32_16x16x32_bf16(pa, vf, of[ni], 0, 0, 0);
            }
        }
        __syncthreads();
    }

    float rinv[4];
    #pragma unroll
    for (int j = 0; j < 4; ++j) rinv[j] = 1.f / lrun[j];
    const size_t orow = (size_t)b * LQ + qt * 64 + w * 16 + (l >> 4) * 4;
    #pragma unroll
    for (int ni = 0; ni < 4; ++ni) {
        const int col = h * HD + ni * 16 + (l & 15);
        #pragma unroll
        for (int j = 0; j < 4; ++j)
            ab[(orow + j) * DM + col] = f2b(of[ni][j] * rinv[j]);
    }
}

// ---------------------------------------------------------------------------
extern "C" void kernel_launch(void* const* d_in, const int* in_sizes, int n_in,
                              void* d_out, int out_size, void* d_ws, size_t ws_size,
                              hipStream_t stream)
{
    const float* q    = (const float*)d_in[0];
    const float* k    = (const float*)d_in[1];
    const float* v    = (const float*)d_in[2];
    const float* Wq   = (const float*)d_in[3];
    const float* bq   = (const float*)d_in[4];
    const float* Wk   = (const float*)d_in[5];
    const float* bk   = (const float*)d_in[6];
    const float* Wv   = (const float*)d_in[7];
    const float* bv   = (const float*)d_in[8];
    const float* g_q  = (const float*)d_in[9];
    const float* be_q = (const float*)d_in[10];
    const float* g_k  = (const float*)d_in[11];
    const float* be_k = (const float*)d_in[12];
    const float* g_v  = (const float*)d_in[13];
    const float* be_v = (const float*)d_in[14];
    const float* W1   = (const float*)d_in[15];
    const float* b1   = (const float*)d_in[16];
    const float* W2   = (const float*)d_in[17];
    const float* b2   = (const float*)d_in[18];

    float* outp = (float*)d_out;
    float* res  = outp + (size_t)NR * DM;       // residual = raw qp (f32)

    char* wsb = (char*)d_ws;
    const size_t MB = 1024 * 1024;
    float* kp  = (float*)(wsb);                 // 16 MB
    float* vp  = (float*)(wsb + 16 * MB);       // 16 MB
    u16* qbf = (u16*)(wsb + 32 * MB);           // 8 MB: bf16(q), later qn
    u16* kbf = (u16*)(wsb + 40 * MB);           // 8 MB: bf16(k), later kn
    u16* vbf = (u16*)(wsb + 48 * MB);           // 8 MB: bf16(v), later vn
    u16* WqT = (u16*)(wsb + 56 * MB);
    u16* WkT = WqT + 512 * 512;
    u16* WvT = WkT + 512 * 512;
    u16* W1T = WvT + 512 * 512;
    u16* W2T = W1T + 512 * 512;
    u16* abb = (u16*)kp;                        // attn out reuses kp (dead after LN-k)
    u16* hbb = (u16*)vp;                        // FFN hidden reuses vp (dead after LN-v)

    conv_bf16_kernel<<<2048, 256, 0, stream>>>(q, qbf);
    conv_bf16_kernel<<<2048, 256, 0, stream>>>(k, kbf);
    conv_bf16_kernel<<<2048, 256, 0, stream>>>(v, vbf);

    dim3 tg(8, 8);
    wt_kernel<<<tg, 256, 0, stream>>>(Wq, WqT);
    wt_kernel<<<tg, 256, 0, stream>>>(Wk, WkT);
    wt_kernel<<<tg, 256, 0, stream>>>(Wv, WvT);
    wt_kernel<<<tg, 256, 0, stream>>>(W1, W1T);
    wt_kernel<<<tg, 256, 0, stream>>>(W2, W2T);

    dim3 gg(NR / 128, DM / 128);
    mfma_gemm_kernel<false, false><<<gg, 512, 0, stream>>>(qbf, WqT, bq, res);
    mfma_gemm_kernel<false, false><<<gg, 512, 0, stream>>>(kbf, WkT, bk, kp);
    mfma_gemm_kernel<false, false><<<gg, 512, 0, stream>>>(vbf, WvT, bv, vp);

    ln_bf16_kernel<<<NR, 256, 0, stream>>>(res, g_q, be_q, qbf, 0.125f);  // fold 1/sqrt(64)
    ln_bf16_kernel<<<NR, 256, 0, stream>>>(kp,  g_k, be_k, kbf, 1.f);
    ln_bf16_kernel<<<NR, 256, 0, stream>>>(vp,  g_v, be_v, vbf, 1.f);

    attn_mfma_kernel<<<dim3(16, NH, 8), 256, 0, stream>>>(qbf, kbf, vbf, abb);

    mfma_gemm_kernel<true,  true ><<<gg, 512, 0, stream>>>(abb, W1T, b1, hbb);
    mfma_gemm_kernel<false, false><<<gg, 512, 0, stream>>>(hbb, W2T, b2, outp);
}

// Round 4
// 169.014 us; speedup vs baseline: 5.0348x; 1.1387x over previous
//
#include <hip/hip_runtime.h>
#include <stdint.h>

typedef unsigned short u16;
typedef __attribute__((ext_vector_type(8))) short bf16x8;
typedef __attribute__((ext_vector_type(4))) float f32x4;
typedef __attribute__((ext_vector_type(16))) float f32x16;

#define NR 8192     // B*L rows
#define DM 512      // model dim
#define NH 8
#define HD 64
#define LQ 1024

// fold 1/sqrt(64) * log2(e) into LN-q so scores are in exp2 domain
#define QSCALE (0.125f * 1.4426950408889634f)

__device__ __forceinline__ u16 f2b(float f) {
    union { float f; uint32_t u; } v; v.f = f;
    uint32_t r = v.u + 0x7fffu + ((v.u >> 16) & 1u);   // RNE
    return (u16)(r >> 16);
}
__device__ __forceinline__ uint32_t pk2(float lo, float hi) {
    return (uint32_t)f2b(lo) | ((uint32_t)f2b(hi) << 16);
}

// ---------------------------------------------------------------------------
// f32 -> bf16 bulk convert (8 elems/thread)
// ---------------------------------------------------------------------------
__global__ __launch_bounds__(256)
void conv_bf16_kernel(const float* __restrict__ in, u16* __restrict__ out)
{
    const int i = blockIdx.x * 256 + threadIdx.x;
    const float4* p = (const float4*)in + (size_t)i * 2;
    float4 a = p[0], b = p[1];
    uint4 o;
    o.x = pk2(a.x, a.y);
    o.y = pk2(a.z, a.w);
    o.z = pk2(b.x, b.y);
    o.w = pk2(b.z, b.w);
    ((uint4*)out)[i] = o;
}

// ---------------------------------------------------------------------------
// W [K=512][N=512] f32  ->  Wt [N][K] bf16
// ---------------------------------------------------------------------------
__global__ __launch_bounds__(256)
void wt_kernel(const float* __restrict__ W, u16* __restrict__ Wt)
{
    __shared__ float S[64][65];
    const int k0 = blockIdx.x * 64, n0 = blockIdx.y * 64;
    #pragma unroll
    for (int p = 0; p < 16; ++p) {
        int idx = threadIdx.x + p * 256;
        int r = idx >> 6, c = idx & 63;
        S[r][c] = W[(size_t)(k0 + r) * DM + n0 + c];
    }
    __syncthreads();
    #pragma unroll
    for (int p = 0; p < 16; ++p) {
        int idx = threadIdx.x + p * 256;
        int r = idx >> 6, c = idx & 63;
        Wt[(size_t)(n0 + r) * DM + k0 + c] = f2b(S[c][r]);
    }
}

// ---------------------------------------------------------------------------
// V [row(b,l)][h*64+d] bf16 -> Vt [b][h][d=64][l=1024] bf16 (per-head transpose)
// ---------------------------------------------------------------------------
__global__ __launch_bounds__(256)
void vt_kernel(const u16* __restrict__ vn, u16* __restrict__ vt)
{
    __shared__ u16 S[64][82];
    const int lt = blockIdx.x, bh = blockIdx.y;
    const int b = bh >> 3, h = bh & 7;
    const int t = threadIdx.x;
    {
        const int r = t >> 2, dc = (t & 3) * 16;
        const u16* src = vn + (size_t)(b * LQ + lt * 64 + r) * DM + h * HD + dc;
        *(uint4*)&S[r][dc]     = *(const uint4*)(src);
        *(uint4*)&S[r][dc + 8] = *(const uint4*)(src + 8);
    }
    __syncthreads();
    {
        const int d = t >> 2, lc = (t & 3) * 16;
        u16 tmp[16];
        #pragma unroll
        for (int e = 0; e < 16; ++e) tmp[e] = S[lc + e][d];
        u16* dst = vt + (((size_t)bh * HD + d) << 10) + lt * 64 + lc;
        *(uint4*)dst       = *(uint4*)&tmp[0];
        *(uint4*)(dst + 8) = *(uint4*)&tmp[8];
    }
}

// ---------------------------------------------------------------------------
// LayerNorm rows of 512, f32 in -> bf16 out, gamma/beta scaled by `scale`
// ---------------------------------------------------------------------------
__global__ __launch_bounds__(256)
void ln_bf16_kernel(const float* __restrict__ P, const float* __restrict__ gm,
                    const float* __restrict__ be, u16* __restrict__ out, float scale)
{
    const int row = blockIdx.x, t = threadIdx.x;
    const size_t off = (size_t)row * DM + t * 2;
    float2 v = *(const float2*)(P + off);
    float s = v.x + v.y, s2 = v.x * v.x + v.y * v.y;
    #pragma unroll
    for (int o = 32; o; o >>= 1) { s += __shfl_down(s, o); s2 += __shfl_down(s2, o); }
    __shared__ float ss[4], ss2[4];
    if ((t & 63) == 0) { ss[t >> 6] = s; ss2[t >> 6] = s2; }
    __syncthreads();
    float S = ss[0] + ss[1] + ss[2] + ss[3];
    float S2 = ss2[0] + ss2[1] + ss2[2] + ss2[3];
    float mu = S * (1.f / DM);
    float var = S2 * (1.f / DM) - mu * mu;
    float rs = rsqrtf(var + 1e-6f);
    float g0 = gm[t * 2] * scale, g1 = gm[t * 2 + 1] * scale;
    float b0 = be[t * 2] * scale, b1 = be[t * 2 + 1] * scale;
    float o0 = (v.x - mu) * rs * g0 + b0;
    float o1 = (v.y - mu) * rs * g1 + b1;
    *(uint32_t*)(out + off) = pk2(o0, o1);
}

// ---------------------------------------------------------------------------
// bf16 MFMA GEMM (verified rounds 2-3): C[M,512] = A[M,512]*Bt^T (+bias)(+relu)
// ---------------------------------------------------------------------------
template<bool RELU, bool OUT_BF16>
__global__ __launch_bounds__(512)
void mfma_gemm_kernel(const u16* __restrict__ A, const u16* __restrict__ Bt,
                      const float* __restrict__ bias, void* __restrict__ Cout)
{
    __shared__ u16 Al[4 * 128 * 8];
    __shared__ u16 Bl[4 * 128 * 8];
    const int t = threadIdx.x;
    const int w = t >> 6, l = t & 63;
    const int m0 = blockIdx.x * 128, n0 = blockIdx.y * 128;
    const int sg = w & 3, sr = (w >> 2) * 64;
    const int wm = w >> 2, wn = w & 3;

    const u16* Ap = A  + (size_t)(m0 + sr + l) * DM + sg * 8;
    const u16* Bp = Bt + (size_t)(n0 + sr + l) * DM + sg * 8;
    const int su = (sg * 128 + sr + l) * 8;

    uint4 ga = *(const uint4*)Ap;
    uint4 gb = *(const uint4*)Bp;

    f32x4 acc[4][2];
    #pragma unroll
    for (int mi = 0; mi < 4; ++mi)
        #pragma unroll
        for (int ni = 0; ni < 2; ++ni)
            acc[mi][ni] = {0.f, 0.f, 0.f, 0.f};

    for (int kb = 0; kb < DM / 32; ++kb) {
        __syncthreads();
        *(uint4*)&Al[su] = ga;
        *(uint4*)&Bl[su] = gb;
        if (kb + 1 < DM / 32) {
            ga = *(const uint4*)(Ap + (kb + 1) * 32);
            gb = *(const uint4*)(Bp + (kb + 1) * 32);
        }
        __syncthreads();
        bf16x8 af[4], bfr[2];
        #pragma unroll
        for (int mi = 0; mi < 4; ++mi)
            af[mi] = *(const bf16x8*)&Al[((l >> 4) * 128 + wm * 64 + mi * 16 + (l & 15)) * 8];
        #pragma unroll
        for (int ni = 0; ni < 2; ++ni)
            bfr[ni] = *(const bf16x8*)&Bl[((l >> 4) * 128 + wn * 32 + ni * 16 + (l & 15)) * 8];
        #pragma unroll
        for (int mi = 0; mi < 4; ++mi)
            #pragma unroll
            for (int ni = 0; ni < 2; ++ni)
                acc[mi][ni] = __builtin_amdgcn_mfma_f32_16x16x32_bf16(af[mi], bfr[ni], acc[mi][ni], 0, 0, 0);
    }

    const int cq = l >> 4, cr = l & 15;
    #pragma unroll
    for (int mi = 0; mi < 4; ++mi) {
        const int row = m0 + wm * 64 + mi * 16 + cq * 4;
        #pragma unroll
        for (int ni = 0; ni < 2; ++ni) {
            const int col = n0 + wn * 32 + ni * 16 + cr;
            const float bb = bias[col];
            #pragma unroll
            for (int j = 0; j < 4; ++j) {
                float vv = acc[mi][ni][j] + bb;
                if (RELU) vv = fmaxf(vv, 0.f);
                if (OUT_BF16) ((u16*)Cout)[(size_t)(row + j) * DM + col] = f2b(vv);
                else          ((float*)Cout)[(size_t)(row + j) * DM + col] = vv;
            }
        }
    }
}

// ---------------------------------------------------------------------------
// MFMA flash attention, swapped-operand 32x32x16, P^T via per-wave LDS.
// Block = 256 q-rows x (b,h); 8 warps x 32 q-rows; KV tile 64.
// Lane owns q-row (l&31): S^T = mfma(K,Q) -> P half-row in regs; softmax
// in-lane + one shfl_xor(32); P^T granule-layout LDS round-trip (paired
// uint32 stores, contiguous b128 reads); O^T = mfma(V^T, P^T).
// K double-buffered in LDS units [gd(8)][kv(64)]; V from pre-transposed
// global Vt[bh][64][1024].
// ---------------------------------------------------------------------------
__global__ __launch_bounds__(512, 2)
void attn_mfma_kernel(const u16* __restrict__ qn, const u16* __restrict__ kn,
                      const u16* __restrict__ vt, u16* __restrict__ ab)
{
    __shared__ u16 Kl[2][8 * 64 * 8];   // 16 KB, K ping-pong
    __shared__ u16 Pl[8][8 * 32 * 8];   // 32 KB, per-wave P^T

    const int t = threadIdx.x;
    const int w = t >> 6, l = t & 63;
    const int hi = l >> 5, ln = l & 31;
    const int qt = blockIdx.x, h = blockIdx.y, b = blockIdx.z;
    const size_t bbase = (size_t)b * LQ * DM + h * HD;
    const int q0 = qt * 256 + w * 32;

    // Q B-fragments: qf[c][e] = Q[q0+ln][c*16 + hi*8 + e]
    bf16x8 qf[4];
    {
        const u16* qp = qn + bbase + (size_t)(q0 + ln) * DM + hi * 8;
        #pragma unroll
        for (int c = 0; c < 4; ++c)
            qf[c] = *(const bf16x8*)(qp + c * 16);
    }

    const u16* Vb = vt + ((((size_t)(b * NH + h)) * HD + ln) << 10);
    const u16* Kg = kn + bbase + (size_t)l * DM + w * 8;
    u16* Pw = &Pl[w][0];

    f32x16 oa0, oa1;
    #pragma unroll
    for (int r = 0; r < 16; ++r) { oa0[r] = 0.f; oa1[r] = 0.f; }
    float mrun = -1e30f, lrun = 0.f;

    *(uint4*)&Kl[0][t * 8] = *(const uint4*)Kg;          // tile 0 staged
    uint4 ka = *(const uint4*)(Kg + (size_t)64 * DM);    // tile 1 in flight
    int cur = 0;

    for (int kt = 0; kt < 16; ++kt) {
        __syncthreads();    // Kl[cur] visible; prior reads of Kl[cur^1] done

        // V^T A-fragments (global, L2-resident); issue early to hide latency
        uint4 vfr[4][2];
        #pragma unroll
        for (int ks = 0; ks < 4; ++ks)
            #pragma unroll
            for (int dh = 0; dh < 2; ++dh)
                vfr[ks][dh] = *(const uint4*)(Vb + (((size_t)dh * 32) << 10)
                                              + kt * 64 + ks * 16 + hi * 8);

        // ---- S^T[kv][q] = sum_d K[kv][d] Q[q][d]  (scale folded into LN-q)
        f32x16 sa0, sa1;
        #pragma unroll
        for (int r = 0; r < 16; ++r) { sa0[r] = 0.f; sa1[r] = 0.f; }
        #pragma unroll
        for (int c = 0; c < 4; ++c) {
            bf16x8 k0 = *(const bf16x8*)&Kl[cur][((c * 2 + hi) * 64 + ln) * 8];
            bf16x8 k1 = *(const bf16x8*)&Kl[cur][((c * 2 + hi) * 64 + 32 + ln) * 8];
            sa0 = __builtin_amdgcn_mfma_f32_32x32x16_bf16(k0, qf[c], sa0, 0, 0, 0);
            sa1 = __builtin_amdgcn_mfma_f32_32x32x16_bf16(k1, qf[c], sa1, 0, 0, 0);
        }

        // stage next K tile into the other buffer; issue kt+2 load
        if (kt < 15) {
            *(uint4*)&Kl[cur ^ 1][t * 8] = ka;
            if (kt < 14) ka = *(const uint4*)(Kg + (size_t)(kt + 2) * 64 * DM);
        }

        // ---- online softmax, exp2 domain, in-lane for q = l&31
        float tmax = -1e30f;
        #pragma unroll
        for (int r = 0; r < 16; ++r) tmax = fmaxf(tmax, fmaxf(sa0[r], sa1[r]));
        tmax = fmaxf(tmax, __shfl_xor(tmax, 32, 64));
        float mnew = fmaxf(mrun, tmax);
        float alpha = __builtin_amdgcn_exp2f(mrun - mnew);
        float psum = 0.f;
        #pragma unroll
        for (int r = 0; r < 16; ++r) {
            sa0[r] = __builtin_amdgcn_exp2f(sa0[r] - mnew);
            sa1[r] = __builtin_amdgcn_exp2f(sa1[r] - mnew);
            psum += sa0[r] + sa1[r];
        }
        psum += __shfl_xor(psum, 32, 64);
        lrun = lrun * alpha + psum;
        mrun = mnew;
        #pragma unroll
        for (int r = 0; r < 16; ++r) { oa0[r] *= alpha; oa1[r] *= alpha; }

        // ---- P^T -> per-wave LDS, granule layout [gkv(8)][q(32)][slot(8)]
        // value sa0[r] is P[q=ln][kv=crow(r,hi)], crow = (r&3)+8*(r>>2)+4*hi
        #pragma unroll
        for (int j = 0; j < 8; ++j) {
            const int r = 2 * j;
            const int slot = (r & 3) + 4 * hi;
            const int g0 = r >> 2;
            *(uint32_t*)&Pw[(g0 * 32 + ln) * 8 + slot]       = pk2(sa0[r], sa0[r + 1]);
            *(uint32_t*)&Pw[((g0 + 4) * 32 + ln) * 8 + slot] = pk2(sa1[r], sa1[r + 1]);
        }

        // ---- O^T += V^T * P^T   (wave-local LDS read, no barrier needed)
        #pragma unroll
        for (int ks = 0; ks < 4; ++ks) {
            bf16x8 pa = *(const bf16x8*)&Pw[((ks * 2 + hi) * 32 + ln) * 8];
            union { uint4 u; bf16x8 v; } v0, v1;
            v0.u = vfr[ks][0]; v1.u = vfr[ks][1];
            oa0 = __builtin_amdgcn_mfma_f32_32x32x16_bf16(v0.v, pa, oa0, 0, 0, 0);
            oa1 = __builtin_amdgcn_mfma_f32_32x32x16_bf16(v1.v, pa, oa1, 0, 0, 0);
        }
        cur ^= 1;
    }

    // ---- epilogue: oa0[r] = O^T[d=crow(r,hi)][q=ln], oa1: d+32
    const float rinv = 1.f / lrun;
    u16* op = ab + (size_t)(b * LQ + q0 + ln) * DM + h * HD;
    #pragma unroll
    for (int g = 0; g < 4; ++g) {
        uint2 s0, s1;
        s0.x = pk2(oa0[4 * g] * rinv, oa0[4 * g + 1] * rinv);
        s0.y = pk2(oa0[4 * g + 2] * rinv, oa0[4 * g + 3] * rinv);
        s1.x = pk2(oa1[4 * g] * rinv, oa1[4 * g + 1] * rinv);
        s1.y = pk2(oa1[4 * g + 2] * rinv, oa1[4 * g + 3] * rinv);
        *(uint2*)(op + 8 * g + 4 * hi)      = s0;
        *(uint2*)(op + 32 + 8 * g + 4 * hi) = s1;
    }
}

// ---------------------------------------------------------------------------
extern "C" void kernel_launch(void* const* d_in, const int* in_sizes, int n_in,
                              void* d_out, int out_size, void* d_ws, size_t ws_size,
                              hipStream_t stream)
{
    const float* q    = (const float*)d_in[0];
    const float* k    = (const float*)d_in[1];
    const float* v    = (const float*)d_in[2];
    const float* Wq   = (const float*)d_in[3];
    const float* bq   = (const float*)d_in[4];
    const float* Wk   = (const float*)d_in[5];
    const float* bk   = (const float*)d_in[6];
    const float* Wv   = (const float*)d_in[7];
    const float* bv   = (const float*)d_in[8];
    const float* g_q  = (const float*)d_in[9];
    const float* be_q = (const float*)d_in[10];
    const float* g_k  = (const float*)d_in[11];
    const float* be_k = (const float*)d_in[12];
    const float* g_v  = (const float*)d_in[13];
    const float* be_v = (const float*)d_in[14];
    const float* W1   = (const float*)d_in[15];
    const float* b1   = (const float*)d_in[16];
    const float* W2   = (const float*)d_in[17];
    const float* b2   = (const float*)d_in[18];

    float* outp = (float*)d_out;
    float* res  = outp + (size_t)NR * DM;       // residual = raw qp (f32)

    char* wsb = (char*)d_ws;
    const size_t MB = 1024 * 1024;
    float* kp  = (float*)(wsb);                 // 16 MB (f32 kp)
    float* vp  = (float*)(wsb + 16 * MB);       // 16 MB (f32 vp)
    u16* qbf = (u16*)(wsb + 32 * MB);           // 8 MB: bf16(q), later qn
    u16* kbf = (u16*)(wsb + 40 * MB);           // 8 MB: bf16(k), later kn
    u16* vbf = (u16*)(wsb + 48 * MB);           // 8 MB: bf16(v), later vn
    u16* WqT = (u16*)(wsb + 56 * MB);
    u16* WkT = WqT + 512 * 512;
    u16* WvT = WkT + 512 * 512;
    u16* W1T = WvT + 512 * 512;
    u16* W2T = W1T + 512 * 512;
    u16* abb = (u16*)kp;                        // attn out (8MB) reuses kp
    u16* hbb = (u16*)vp;                        // FFN hidden (8MB), first half of vp
    u16* vtb = (u16*)(wsb + 24 * MB);           // V^T (8MB), second half of vp

    conv_bf16_kernel<<<2048, 256, 0, stream>>>(q, qbf);
    conv_bf16_kernel<<<2048, 256, 0, stream>>>(k, kbf);
    conv_bf16_kernel<<<2048, 256, 0, stream>>>(v, vbf);

    dim3 tg(8, 8);
    wt_kernel<<<tg, 256, 0, stream>>>(Wq, WqT);
    wt_kernel<<<tg, 256, 0, stream>>>(Wk, WkT);
    wt_kernel<<<tg, 256, 0, stream>>>(Wv, WvT);
    wt_kernel<<<tg, 256, 0, stream>>>(W1, W1T);
    wt_kernel<<<tg, 256, 0, stream>>>(W2, W2T);

    dim3 gg(NR / 128, DM / 128);
    mfma_gemm_kernel<false, false><<<gg, 512, 0, stream>>>(qbf, WqT, bq, res);
    mfma_gemm_kernel<false, false><<<gg, 512, 0, stream>>>(kbf, WkT, bk, kp);
    mfma_gemm_kernel<false, false><<<gg, 512, 0, stream>>>(vbf, WvT, bv, vp);

    ln_bf16_kernel<<<NR, 256, 0, stream>>>(res, g_q, be_q, qbf, QSCALE);
    ln_bf16_kernel<<<NR, 256, 0, stream>>>(kp,  g_k, be_k, kbf, 1.f);
    ln_bf16_kernel<<<NR, 256, 0, stream>>>(vp,  g_v, be_v, vbf, 1.f);

    vt_kernel<<<dim3(16, 64), 256, 0, stream>>>(vbf, vtb);

    attn_mfma_kernel<<<dim3(LQ / 256, NH, 8), 512, 0, stream>>>(qbf, kbf, vtb, abb);

    mfma_gemm_kernel<true,  true ><<<gg, 512, 0, stream>>>(abb, W1T, b1, hbb);
    mfma_gemm_kernel<false, false><<<gg, 512, 0, stream>>>(hbb, W2T, b2, outp);
}

// Round 5
// 144.566 us; speedup vs baseline: 5.8863x; 1.1691x over previous
//
#include <hip/hip_runtime.h>
#include <hip/hip_bf16.h>
#include <stdint.h>

typedef unsigned short u16;
typedef __attribute__((ext_vector_type(8))) short bf16x8;
typedef __attribute__((ext_vector_type(4))) float f32x4;
typedef __attribute__((ext_vector_type(16))) float f32x16;

#define NR 8192     // B*L rows
#define DM 512      // model dim
#define NH 8
#define HD 64
#define LQ 1024

// fold 1/sqrt(64) * log2(e) into LN-q so scores are in exp2 domain
#define QSCALE (0.125f * 1.4426950408889634f)
// fixed softmax offset (safe: |s| <= 512*0.125*log2e = 92 by Cauchy-Schwarz)
#define SOFF 16.0f

__device__ __forceinline__ u16 f2b(float f) {
    union { float f; uint32_t u; } v; v.f = f;
    uint32_t r = v.u + 0x7fffu + ((v.u >> 16) & 1u);   // RNE
    return (u16)(r >> 16);
}
// packed f32x2 -> bf16x2 via official intrinsic (v_cvt_pk_bf16_f32, RNE)
__device__ __forceinline__ uint32_t pk2(float lo, float hi) {
    __hip_bfloat162 h = __float22bfloat162_rn(make_float2(lo, hi));
    union { __hip_bfloat162 h; uint32_t u; } c; c.h = h;
    return c.u;
}

// ---------------------------------------------------------------------------
// f32 -> bf16 bulk convert, fused q/k/v (8 elems/thread), grid (2048, 3)
// ---------------------------------------------------------------------------
__global__ __launch_bounds__(256)
void conv3_kernel(const float* __restrict__ q, const float* __restrict__ k,
                  const float* __restrict__ v, u16* __restrict__ qo,
                  u16* __restrict__ ko, u16* __restrict__ vo)
{
    const int y = blockIdx.y;
    const float* in = y == 0 ? q : y == 1 ? k : v;
    u16* out = y == 0 ? qo : y == 1 ? ko : vo;
    const int i = blockIdx.x * 256 + threadIdx.x;
    const float4* p = (const float4*)in + (size_t)i * 2;
    float4 a = p[0], b = p[1];
    uint4 o;
    o.x = pk2(a.x, a.y);
    o.y = pk2(a.z, a.w);
    o.z = pk2(b.x, b.y);
    o.w = pk2(b.z, b.w);
    ((uint4*)out)[i] = o;
}

// ---------------------------------------------------------------------------
// W [K=512][N=512] f32 -> Wt [N][K] bf16, fused x5, grid (8, 8, 5)
// ---------------------------------------------------------------------------
__global__ __launch_bounds__(256)
void wt5_kernel(const float* __restrict__ W0, const float* __restrict__ W1,
                const float* __restrict__ W2, const float* __restrict__ W3,
                const float* __restrict__ W4,
                u16* __restrict__ T0, u16* __restrict__ T1, u16* __restrict__ T2,
                u16* __restrict__ T3, u16* __restrict__ T4)
{
    const int z = blockIdx.z;
    const float* W = z == 0 ? W0 : z == 1 ? W1 : z == 2 ? W2 : z == 3 ? W3 : W4;
    u16* Wt = z == 0 ? T0 : z == 1 ? T1 : z == 2 ? T2 : z == 3 ? T3 : T4;

    __shared__ float S[64][65];
    const int k0 = blockIdx.x * 64, n0 = blockIdx.y * 64;
    #pragma unroll
    for (int p = 0; p < 16; ++p) {
        int idx = threadIdx.x + p * 256;
        int r = idx >> 6, c = idx & 63;
        S[r][c] = W[(size_t)(k0 + r) * DM + n0 + c];
    }
    __syncthreads();
    #pragma unroll
    for (int p = 0; p < 16; ++p) {
        int idx = threadIdx.x + p * 256;
        int r = idx >> 6, c = idx & 63;
        Wt[(size_t)(n0 + r) * DM + k0 + c] = f2b(S[c][r]);
    }
}

// ---------------------------------------------------------------------------
// V [row(b,l)][h*64+d] bf16 -> Vt [b][h][d=64][l=1024] bf16
// ---------------------------------------------------------------------------
__global__ __launch_bounds__(256)
void vt_kernel(const u16* __restrict__ vn, u16* __restrict__ vt)
{
    __shared__ u16 S[64][82];
    const int lt = blockIdx.x, bh = blockIdx.y;
    const int b = bh >> 3, h = bh & 7;
    const int t = threadIdx.x;
    {
        const int r = t >> 2, dc = (t & 3) * 16;
        const u16* src = vn + (size_t)(b * LQ + lt * 64 + r) * DM + h * HD + dc;
        *(uint4*)&S[r][dc]     = *(const uint4*)(src);
        *(uint4*)&S[r][dc + 8] = *(const uint4*)(src + 8);
    }
    __syncthreads();
    {
        const int d = t >> 2, lc = (t & 3) * 16;
        u16 tmp[16];
        #pragma unroll
        for (int e = 0; e < 16; ++e) tmp[e] = S[lc + e][d];
        u16* dst = vt + (((size_t)bh * HD + d) << 10) + lt * 64 + lc;
        *(uint4*)dst       = *(uint4*)&tmp[0];
        *(uint4*)(dst + 8) = *(uint4*)&tmp[8];
    }
}

// ---------------------------------------------------------------------------
// LayerNorm rows of 512, f32 in -> bf16 out, fused q/k/v, grid (NR, 3)
// ---------------------------------------------------------------------------
__global__ __launch_bounds__(256)
void ln3_kernel(const float* __restrict__ Pq, const float* __restrict__ Pk,
                const float* __restrict__ Pv,
                const float* __restrict__ gq, const float* __restrict__ bq,
                const float* __restrict__ gk, const float* __restrict__ bk,
                const float* __restrict__ gv, const float* __restrict__ bv,
                u16* __restrict__ oq, u16* __restrict__ ok, u16* __restrict__ ov)
{
    const int y = blockIdx.y;
    const float* P  = y == 0 ? Pq : y == 1 ? Pk : Pv;
    const float* gm = y == 0 ? gq : y == 1 ? gk : gv;
    const float* be = y == 0 ? bq : y == 1 ? bk : bv;
    u16* out = y == 0 ? oq : y == 1 ? ok : ov;
    const float scale = y == 0 ? QSCALE : 1.f;

    const int row = blockIdx.x, t = threadIdx.x;
    const size_t off = (size_t)row * DM + t * 2;
    float2 v = *(const float2*)(P + off);
    float s = v.x + v.y, s2 = v.x * v.x + v.y * v.y;
    #pragma unroll
    for (int o = 32; o; o >>= 1) { s += __shfl_down(s, o); s2 += __shfl_down(s2, o); }
    __shared__ float ss[4], ss2[4];
    if ((t & 63) == 0) { ss[t >> 6] = s; ss2[t >> 6] = s2; }
    __syncthreads();
    float S = ss[0] + ss[1] + ss[2] + ss[3];
    float S2 = ss2[0] + ss2[1] + ss2[2] + ss2[3];
    float mu = S * (1.f / DM);
    float var = S2 * (1.f / DM) - mu * mu;
    float rs = rsqrtf(var + 1e-6f);
    float g0 = gm[t * 2] * scale, g1 = gm[t * 2 + 1] * scale;
    float b0 = be[t * 2] * scale, b1 = be[t * 2 + 1] * scale;
    float o0 = (v.x - mu) * rs * g0 + b0;
    float o1 = (v.y - mu) * rs * g1 + b1;
    *(uint32_t*)(out + off) = pk2(o0, o1);
}

// ---------------------------------------------------------------------------
// bf16 MFMA GEMM body (verified rounds 2-4): C[M,512] = A*Bt^T (+bias)(+relu)
// ---------------------------------------------------------------------------
template<bool RELU, bool OUT_BF16>
__device__ __forceinline__
void gemm_body(const u16* __restrict__ A, const u16* __restrict__ Bt,
               const float* __restrict__ bias, void* __restrict__ Cout)
{
    __shared__ u16 Al[4 * 128 * 8];
    __shared__ u16 Bl[4 * 128 * 8];
    const int t = threadIdx.x;
    const int w = t >> 6, l = t & 63;
    const int m0 = blockIdx.x * 128, n0 = blockIdx.y * 128;
    const int sg = w & 3, sr = (w >> 2) * 64;
    const int wm = w >> 2, wn = w & 3;

    const u16* Ap = A  + (size_t)(m0 + sr + l) * DM + sg * 8;
    const u16* Bp = Bt + (size_t)(n0 + sr + l) * DM + sg * 8;
    const int su = (sg * 128 + sr + l) * 8;

    uint4 ga = *(const uint4*)Ap;
    uint4 gb = *(const uint4*)Bp;

    f32x4 acc[4][2];
    #pragma unroll
    for (int mi = 0; mi < 4; ++mi)
        #pragma unroll
        for (int ni = 0; ni < 2; ++ni)
            acc[mi][ni] = {0.f, 0.f, 0.f, 0.f};

    for (int kb = 0; kb < DM / 32; ++kb) {
        __syncthreads();
        *(uint4*)&Al[su] = ga;
        *(uint4*)&Bl[su] = gb;
        if (kb + 1 < DM / 32) {
            ga = *(const uint4*)(Ap + (kb + 1) * 32);
            gb = *(const uint4*)(Bp + (kb + 1) * 32);
        }
        __syncthreads();
        bf16x8 af[4], bfr[2];
        #pragma unroll
        for (int mi = 0; mi < 4; ++mi)
            af[mi] = *(const bf16x8*)&Al[((l >> 4) * 128 + wm * 64 + mi * 16 + (l & 15)) * 8];
        #pragma unroll
        for (int ni = 0; ni < 2; ++ni)
            bfr[ni] = *(const bf16x8*)&Bl[((l >> 4) * 128 + wn * 32 + ni * 16 + (l & 15)) * 8];
        #pragma unroll
        for (int mi = 0; mi < 4; ++mi)
            #pragma unroll
            for (int ni = 0; ni < 2; ++ni)
                acc[mi][ni] = __builtin_amdgcn_mfma_f32_16x16x32_bf16(af[mi], bfr[ni], acc[mi][ni], 0, 0, 0);
    }

    const int cq = l >> 4, cr = l & 15;
    #pragma unroll
    for (int mi = 0; mi < 4; ++mi) {
        const int row = m0 + wm * 64 + mi * 16 + cq * 4;
        #pragma unroll
        for (int ni = 0; ni < 2; ++ni) {
            const int col = n0 + wn * 32 + ni * 16 + cr;
            const float bb = bias[col];
            #pragma unroll
            for (int j = 0; j < 4; ++j) {
                float vv = acc[mi][ni][j] + bb;
                if (RELU) vv = fmaxf(vv, 0.f);
                if (OUT_BF16) ((u16*)Cout)[(size_t)(row + j) * DM + col] = f2b(vv);
                else          ((float*)Cout)[(size_t)(row + j) * DM + col] = vv;
            }
        }
    }
}

template<bool RELU, bool OUT_BF16>
__global__ __launch_bounds__(512)
void mfma_gemm_kernel(const u16* __restrict__ A, const u16* __restrict__ Bt,
                      const float* __restrict__ bias, void* __restrict__ Cout)
{
    gemm_body<RELU, OUT_BF16>(A, Bt, bias, Cout);
}

// fused q/k/v projection GEMM, grid (64, 4, 3)
__global__ __launch_bounds__(512)
void gemm_qkv_kernel(const u16* __restrict__ qbf, const u16* __restrict__ kbf,
                     const u16* __restrict__ vbf,
                     const u16* __restrict__ WqT, const u16* __restrict__ WkT,
                     const u16* __restrict__ WvT,
                     const float* __restrict__ bq, const float* __restrict__ bk,
                     const float* __restrict__ bv,
                     float* __restrict__ res, float* __restrict__ kp,
                     float* __restrict__ vp)
{
    const int z = blockIdx.z;
    const u16* A    = z == 0 ? qbf : z == 1 ? kbf : vbf;
    const u16* Bt   = z == 0 ? WqT : z == 1 ? WkT : WvT;
    const float* bb = z == 0 ? bq  : z == 1 ? bk  : bv;
    void* C         = z == 0 ? (void*)res : z == 1 ? (void*)kp : (void*)vp;
    gemm_body<false, false>(A, Bt, bb, C);
}

// ---------------------------------------------------------------------------
// MFMA flash attention, swapped-operand 32x32x16, fixed-offset softmax.
// Block = 256 q-rows x (b,h); 8 warps x 32 q-rows; KV tile 64.
// Lane owns q-row (l&31): S^T = mfma(K,Q) with C-init = -SOFF; P = exp2(S^T)
// in-lane (no max tracking: |s| <= 92 provably); l accumulated per-lane,
// one shfl_xor(32) at the end. P^T via per-wave LDS granule layout
// (cvt_pk pairs, b64 stores); O^T = mfma(V^T, P^T). K double-buffered in
// LDS; V from pre-transposed global Vt[bh][64][1024].
// ---------------------------------------------------------------------------
__global__ __launch_bounds__(512, 2)
void attn_mfma_kernel(const u16* __restrict__ qn, const u16* __restrict__ kn,
                      const u16* __restrict__ vt, u16* __restrict__ ab)
{
    __shared__ u16 Kl[2][8 * 64 * 8];   // 16 KB, K ping-pong
    __shared__ u16 Pl[8][8 * 32 * 8];   // 32 KB, per-wave P^T

    const int t = threadIdx.x;
    const int w = t >> 6, l = t & 63;
    const int hi = l >> 5, ln = l & 31;
    const int qt = blockIdx.x, h = blockIdx.y, b = blockIdx.z;
    const size_t bbase = (size_t)b * LQ * DM + h * HD;
    const int q0 = qt * 256 + w * 32;

    // Q B-fragments: qf[c][e] = Q[q0+ln][c*16 + hi*8 + e]
    bf16x8 qf[4];
    {
        const u16* qp = qn + bbase + (size_t)(q0 + ln) * DM + hi * 8;
        #pragma unroll
        for (int c = 0; c < 4; ++c)
            qf[c] = *(const bf16x8*)(qp + c * 16);
    }

    const u16* Vb = vt + ((((size_t)(b * NH + h)) * HD + ln) << 10);
    const u16* Kg = kn + bbase + (size_t)l * DM + w * 8;
    u16* Pw = &Pl[w][0];

    f32x16 oa0, oa1;
    #pragma unroll
    for (int r = 0; r < 16; ++r) { oa0[r] = 0.f; oa1[r] = 0.f; }
    float lsum = 0.f;

    *(uint4*)&Kl[0][t * 8] = *(const uint4*)Kg;          // tile 0 staged
    uint4 ka = *(const uint4*)(Kg + (size_t)64 * DM);    // tile 1 in flight
    int cur = 0;

    for (int kt = 0; kt < 16; ++kt) {
        __syncthreads();    // Kl[cur] visible; prior reads of Kl[cur^1] done

        // V^T A-fragments (global, L2-resident); issue early to hide latency
        uint4 vfr[4][2];
        #pragma unroll
        for (int ks = 0; ks < 4; ++ks)
            #pragma unroll
            for (int dh = 0; dh < 2; ++dh)
                vfr[ks][dh] = *(const uint4*)(Vb + (((size_t)dh * 32) << 10)
                                              + kt * 64 + ks * 16 + hi * 8);

        // ---- S^T[kv][q] - SOFF = sum_d K[kv][d] Q[q][d] - SOFF
        f32x16 sa0, sa1;
        #pragma unroll
        for (int r = 0; r < 16; ++r) { sa0[r] = -SOFF; sa1[r] = -SOFF; }
        #pragma unroll
        for (int c = 0; c < 4; ++c) {
            bf16x8 k0 = *(const bf16x8*)&Kl[cur][((c * 2 + hi) * 64 + ln) * 8];
            bf16x8 k1 = *(const bf16x8*)&Kl[cur][((c * 2 + hi) * 64 + 32 + ln) * 8];
            sa0 = __builtin_amdgcn_mfma_f32_32x32x16_bf16(k0, qf[c], sa0, 0, 0, 0);
            sa1 = __builtin_amdgcn_mfma_f32_32x32x16_bf16(k1, qf[c], sa1, 0, 0, 0);
        }

        // stage next K tile into the other buffer; issue kt+2 load
        if (kt < 15) {
            *(uint4*)&Kl[cur ^ 1][t * 8] = ka;
            if (kt < 14) ka = *(const uint4*)(Kg + (size_t)(kt + 2) * 64 * DM);
        }

        // ---- P = exp2(s - SOFF); accumulate per-lane l
        #pragma unroll
        for (int r = 0; r < 16; ++r) {
            sa0[r] = __builtin_amdgcn_exp2f(sa0[r]);
            sa1[r] = __builtin_amdgcn_exp2f(sa1[r]);
            lsum += sa0[r] + sa1[r];
        }

        // ---- P^T -> per-wave LDS, granule layout [gkv(8)][q(32)][slot(8)]
        // value sa0[r] is P[q=ln][kv=crow(r,hi)], crow = (r&3)+8*(r>>2)+4*hi
        #pragma unroll
        for (int g0 = 0; g0 < 4; ++g0) {
            uint2 w0, w1;
            w0.x = pk2(sa0[4 * g0],     sa0[4 * g0 + 1]);
            w0.y = pk2(sa0[4 * g0 + 2], sa0[4 * g0 + 3]);
            w1.x = pk2(sa1[4 * g0],     sa1[4 * g0 + 1]);
            w1.y = pk2(sa1[4 * g0 + 2], sa1[4 * g0 + 3]);
            *(uint2*)&Pw[(g0 * 32 + ln) * 8 + 4 * hi]       = w0;
            *(uint2*)&Pw[((g0 + 4) * 32 + ln) * 8 + 4 * hi] = w1;
        }

        // ---- O^T += V^T * P^T   (wave-local LDS read, no barrier needed)
        #pragma unroll
        for (int ks = 0; ks < 4; ++ks) {
            bf16x8 pa = *(const bf16x8*)&Pw[((ks * 2 + hi) * 32 + ln) * 8];
            union { uint4 u; bf16x8 v; } v0, v1;
            v0.u = vfr[ks][0]; v1.u = vfr[ks][1];
            oa0 = __builtin_amdgcn_mfma_f32_32x32x16_bf16(v0.v, pa, oa0, 0, 0, 0);
            oa1 = __builtin_amdgcn_mfma_f32_32x32x16_bf16(v1.v, pa, oa1, 0, 0, 0);
        }
        cur ^= 1;
    }

    // ---- epilogue: oa0[r] = O^T[d=crow(r,hi)][q=ln], oa1: d+32
    lsum += __shfl_xor(lsum, 32, 64);
    const float rinv = 1.f / lsum;
    u16* op = ab + (size_t)(b * LQ + q0 + ln) * DM + h * HD;
    #pragma unroll
    for (int g = 0; g < 4; ++g) {
        uint2 s0, s1;
        s0.x = pk2(oa0[4 * g] * rinv, oa0[4 * g + 1] * rinv);
        s0.y = pk2(oa0[4 * g + 2] * rinv, oa0[4 * g + 3] * rinv);
        s1.x = pk2(oa1[4 * g] * rinv, oa1[4 * g + 1] * rinv);
        s1.y = pk2(oa1[4 * g + 2] * rinv, oa1[4 * g + 3] * rinv);
        *(uint2*)(op + 8 * g + 4 * hi)      = s0;
        *(uint2*)(op + 32 + 8 * g + 4 * hi) = s1;
    }
}

// ---------------------------------------------------------------------------
extern "C" void kernel_launch(void* const* d_in, const int* in_sizes, int n_in,
                              void* d_out, int out_size, void* d_ws, size_t ws_size,
                              hipStream_t stream)
{
    const float* q    = (const float*)d_in[0];
    const float* k    = (const float*)d_in[1];
    const float* v    = (const float*)d_in[2];
    const float* Wq   = (const float*)d_in[3];
    const float* bq   = (const float*)d_in[4];
    const float* Wk   = (const float*)d_in[5];
    const float* bk   = (const float*)d_in[6];
    const float* Wv   = (const float*)d_in[7];
    const float* bv   = (const float*)d_in[8];
    const float* g_q  = (const float*)d_in[9];
    const float* be_q = (const float*)d_in[10];
    const float* g_k  = (const float*)d_in[11];
    const float* be_k = (const float*)d_in[12];
    const float* g_v  = (const float*)d_in[13];
    const float* be_v = (const float*)d_in[14];
    const float* W1   = (const float*)d_in[15];
    const float* b1   = (const float*)d_in[16];
    const float* W2   = (const float*)d_in[17];
    const float* b2   = (const float*)d_in[18];

    float* outp = (float*)d_out;
    float* res  = outp + (size_t)NR * DM;       // residual = raw qp (f32)

    char* wsb = (char*)d_ws;
    const size_t MB = 1024 * 1024;
    float* kp  = (float*)(wsb);                 // 16 MB (f32 kp)
    float* vp  = (float*)(wsb + 16 * MB);       // 16 MB (f32 vp)
    u16* qbf = (u16*)(wsb + 32 * MB);           // 8 MB: bf16(q), later qn
    u16* kbf = (u16*)(wsb + 40 * MB);           // 8 MB: bf16(k), later kn
    u16* vbf = (u16*)(wsb + 48 * MB);           // 8 MB: bf16(v), later vn
    u16* WqT = (u16*)(wsb + 56 * MB);
    u16* WkT = WqT + 512 * 512;
    u16* WvT = WkT + 512 * 512;
    u16* W1T = WvT + 512 * 512;
    u16* W2T = W1T + 512 * 512;
    u16* abb = (u16*)kp;                        // attn out (8MB) reuses kp
    u16* hbb = (u16*)vp;                        // FFN hidden (8MB), first half of vp
    u16* vtb = (u16*)(wsb + 24 * MB);           // V^T (8MB), second half of vp

    conv3_kernel<<<dim3(2048, 3), 256, 0, stream>>>(q, k, v, qbf, kbf, vbf);

    wt5_kernel<<<dim3(8, 8, 5), 256, 0, stream>>>(Wq, Wk, Wv, W1, W2,
                                                  WqT, WkT, WvT, W1T, W2T);

    gemm_qkv_kernel<<<dim3(NR / 128, DM / 128, 3), 512, 0, stream>>>(
        qbf, kbf, vbf, WqT, WkT, WvT, bq, bk, bv, res, kp, vp);

    ln3_kernel<<<dim3(NR, 3), 256, 0, stream>>>(res, kp, vp,
                                                g_q, be_q, g_k, be_k, g_v, be_v,
                                                qbf, kbf, vbf);

    vt_kernel<<<dim3(16, 64), 256, 0, stream>>>(vbf, vtb);

    attn_mfma_kernel<<<dim3(LQ / 256, NH, 8), 512, 0, stream>>>(qbf, kbf, vtb, abb);

    dim3 gg(NR / 128, DM / 128);
    mfma_gemm_kernel<true,  true ><<<gg, 512, 0, stream>>>(abb, W1T, b1, (void*)hbb);
    mfma_gemm_kernel<false, false><<<gg, 512, 0, stream>>>(hbb, W2T, b2, (void*)outp);
}